// Round 1
// baseline (584.487 us; speedup 1.0000x reference)
//
#include <hip/hip_runtime.h>

// Head attention forward, MI355X gfx950.
// B=8, T=2048, C=1024, H=64. Scale = C^-0.5 = 1/32.
// Round 1 structure:
//   kernel 1: qkv_proj  fp32 FMA GEMM [16384x1024]@[1024x64]x3 -> bf16 q,k,vt in ws
//   kernel 2: flash     bf16-MFMA flash attention, 16-row q-tiles, 1 wave/block
//
// ws layout (u16/bf16):
//   [0      , BTH)   k  [b][t][h]
//   [BTH    , 2*BTH) q  [b][t][h]
//   [2*BTH  , 3*BTH) vt [b][h][t]   (transposed so PV B-frags are contiguous)

#define B_ 8
#define T_ 2048
#define C_ 1024
#define H_ 64
#define BTH (B_ * T_ * H_)

typedef unsigned short u16;
typedef float f32x4 __attribute__((ext_vector_type(4)));
typedef __bf16 bf16x8 __attribute__((ext_vector_type(8)));

__device__ __forceinline__ u16 f2bf(float f) {
  union { float f; unsigned u; } c; c.f = f;
  unsigned u = c.u;
  return (u16)((u + 0x7FFFu + ((u >> 16) & 1u)) >> 16);  // RNE
}

// ---------------------------------------------------------------------------
// Kernel 1: q/k/v projection. grid (3, B*T/16), block (64,4).
// g = blockIdx.x: 0->k, 1->q, 2->v(transposed store).
// Each thread: 4 consecutive rows (t) x 1 column (h), K-loop over C=1024.
// Wave spans h (tx) -> W loads coalesced; x loads wave-uniform (broadcast).
// ---------------------------------------------------------------------------
__global__ __launch_bounds__(256)
void qkv_proj(const float* __restrict__ x, const float* __restrict__ Wk,
              const float* __restrict__ Wq, const float* __restrict__ Wv,
              u16* __restrict__ ws) {
  __shared__ u16 tile[64 * 17];  // only used by g==2 (pad 17 kills bank conflicts)
  const int h  = threadIdx.x;    // 0..63
  const int ty = threadIdx.y;    // 0..3
  const int g  = blockIdx.x;     // 0..2
  const int row0 = blockIdx.y * 16 + ty * 4;  // flat row = b*T + t
  const float* __restrict__ W = (g == 0) ? Wk : (g == 1) ? Wq : Wv;
  const float* __restrict__ Wc = W + h;
  const float* __restrict__ xr = x + (size_t)row0 * C_;
  float a0 = 0.f, a1 = 0.f, a2 = 0.f, a3 = 0.f;
#pragma unroll 2
  for (int kk = 0; kk < C_; kk += 4) {
    const float4 xv0 = *(const float4*)(xr + kk);
    const float4 xv1 = *(const float4*)(xr + C_ + kk);
    const float4 xv2 = *(const float4*)(xr + 2 * C_ + kk);
    const float4 xv3 = *(const float4*)(xr + 3 * C_ + kk);
    const float w0 = Wc[(size_t)(kk + 0) * H_];
    const float w1 = Wc[(size_t)(kk + 1) * H_];
    const float w2 = Wc[(size_t)(kk + 2) * H_];
    const float w3 = Wc[(size_t)(kk + 3) * H_];
    a0 = fmaf(xv0.x, w0, fmaf(xv0.y, w1, fmaf(xv0.z, w2, fmaf(xv0.w, w3, a0))));
    a1 = fmaf(xv1.x, w0, fmaf(xv1.y, w1, fmaf(xv1.z, w2, fmaf(xv1.w, w3, a1))));
    a2 = fmaf(xv2.x, w0, fmaf(xv2.y, w1, fmaf(xv2.z, w2, fmaf(xv2.w, w3, a2))));
    a3 = fmaf(xv3.x, w0, fmaf(xv3.y, w1, fmaf(xv3.z, w2, fmaf(xv3.w, w3, a3))));
  }
  if (g < 2) {
    u16* outp = ws + (size_t)g * BTH;
    const size_t o0i = (size_t)row0 * H_ + h;
    outp[o0i]          = f2bf(a0);
    outp[o0i + H_]     = f2bf(a1);
    outp[o0i + 2 * H_] = f2bf(a2);
    outp[o0i + 3 * H_] = f2bf(a3);
  } else {
    // transpose the block's 16(t) x 64(h) result into vt[b][h][t]
    tile[h * 17 + ty * 4 + 0] = f2bf(a0);
    tile[h * 17 + ty * 4 + 1] = f2bf(a1);
    tile[h * 17 + ty * 4 + 2] = f2bf(a2);
    tile[h * 17 + ty * 4 + 3] = f2bf(a3);
    __syncthreads();
    const int tid  = ty * 64 + h;
    const int hrow = tid >> 2;           // 0..63
    const int seg  = tid & 3;            // 4 t-values each
    const int rowb = blockIdx.y * 16;    // flat row base (multiple of 16)
    const int b    = rowb >> 11;         // /2048
    const int tb   = rowb & 2047;
    const u16 w0_ = tile[hrow * 17 + seg * 4 + 0];
    const u16 w1_ = tile[hrow * 17 + seg * 4 + 1];
    const u16 w2_ = tile[hrow * 17 + seg * 4 + 2];
    const u16 w3_ = tile[hrow * 17 + seg * 4 + 3];
    uint2 pk;
    pk.x = (unsigned)w0_ | ((unsigned)w1_ << 16);
    pk.y = (unsigned)w2_ | ((unsigned)w3_ << 16);
    u16* vt = ws + (size_t)2 * BTH + ((size_t)(b * H_ + hrow)) * T_ + tb + seg * 4;
    *(uint2*)vt = pk;
  }
}

// ---------------------------------------------------------------------------
// Kernel 2: flash attention, bf16 MFMA 16x16x32.
// grid (64, B), block 64 (1 wave). Wave handles q-tiles p and 127-p (16 rows
// each) -> uniform ~65 s-tile iterations per wave, 512 blocks.
// Layouts (gfx950 verified):
//   A-frag: A[m=lane&15][k=quad*8+j]   B-frag: B[k=quad*8+j][n=lane&15]
//   C/D:    D[row=quad*4+reg][col=lane&15]
// S = Q*K^T: A=Q rows (contiguous h), B from k[b][s][h] rows (contiguous h).
// O += P*V:  A=P via LDS relayout,     B from vt[b][h][t] rows (contiguous s).
// ---------------------------------------------------------------------------
__global__ __launch_bounds__(64)
void flash(const u16* __restrict__ ws, float* __restrict__ out) {
  const u16* __restrict__ kg = ws;
  const u16* __restrict__ qg = ws + BTH;
  const u16* __restrict__ vt = ws + (size_t)2 * BTH;
  const int b    = blockIdx.y;
  const int lane = threadIdx.x;
  const int l15  = lane & 15;
  const int quad = lane >> 4;
  __shared__ __bf16 Pt[16 * 40];  // stride 40 halfwords: b128-aligned reads, ~2-way banks
  const float SCL = 0.03125f * 1.44269504088896f;  // C^-0.5 * log2(e)

  for (int hlf = 0; hlf < 2; ++hlf) {
    const int qt = hlf ? (127 - (int)blockIdx.x) : (int)blockIdx.x;  // 16-row q-tile
    const int t0 = qt * 16;
    const u16* qrow = qg + ((size_t)(b * T_ + t0 + l15)) * H_ + quad * 8;
    const bf16x8 qf0 = *(const bf16x8*)(qrow);        // h = quad*8..+7
    const bf16x8 qf1 = *(const bf16x8*)(qrow + 32);   // h = 32+quad*8..+7
    f32x4 o0 = {0.f, 0.f, 0.f, 0.f}, o1 = o0, o2 = o0, o3 = o0;
    float mr[4] = {-INFINITY, -INFINITY, -INFINITY, -INFINITY};
    float lr[4] = {0.f, 0.f, 0.f, 0.f};
    const int nst = (qt >> 1) + 1;  // s-tiles of 32 keys

    for (int st = 0; st < nst; ++st) {
      const int s0 = st * 32;
      // ---- S = Q K^T (two 16-col n-tiles, K-dim 64 = 2 mfma each) ----
      const u16* kb = kg + ((size_t)(b * T_ + s0 + l15)) * H_ + quad * 8;
      const bf16x8 bk00 = *(const bf16x8*)(kb);
      const bf16x8 bk01 = *(const bf16x8*)(kb + 32);
      const bf16x8 bk10 = *(const bf16x8*)(kb + 16 * H_);
      const bf16x8 bk11 = *(const bf16x8*)(kb + 16 * H_ + 32);
      const f32x4 z = {0.f, 0.f, 0.f, 0.f};
      f32x4 s0f = __builtin_amdgcn_mfma_f32_16x16x32_bf16(qf0, bk00, z, 0, 0, 0);
      s0f = __builtin_amdgcn_mfma_f32_16x16x32_bf16(qf1, bk01, s0f, 0, 0, 0);
      f32x4 s1f = __builtin_amdgcn_mfma_f32_16x16x32_bf16(qf0, bk10, z, 0, 0, 0);
      s1f = __builtin_amdgcn_mfma_f32_16x16x32_bf16(qf1, bk11, s1f, 0, 0, 0);

      float sc0[4], sc1[4];
#pragma unroll
      for (int r = 0; r < 4; ++r) { sc0[r] = s0f[r] * SCL; sc1[r] = s1f[r] * SCL; }
      if (st == nst - 1) {  // causal mask only possible on the last tile
#pragma unroll
        for (int r = 0; r < 4; ++r) {
          const int t = t0 + quad * 4 + r;
          if (s0 + l15 > t)      sc0[r] = -1e30f;
          if (s0 + 16 + l15 > t) sc1[r] = -1e30f;
        }
      }
      // ---- online softmax (rows live on the 16 lanes of each quad) ----
      float mx[4];
#pragma unroll
      for (int r = 0; r < 4; ++r) mx[r] = fmaxf(sc0[r], sc1[r]);
#pragma unroll
      for (int d = 1; d < 16; d <<= 1)
#pragma unroll
        for (int r = 0; r < 4; ++r) mx[r] = fmaxf(mx[r], __shfl_xor(mx[r], d, 64));
      float alpha[4], p0[4], p1[4], rs[4];
#pragma unroll
      for (int r = 0; r < 4; ++r) {
        const float mn = fmaxf(mr[r], mx[r]);
        alpha[r] = __builtin_amdgcn_exp2f(mr[r] - mn);
        mr[r] = mn;
        p0[r] = __builtin_amdgcn_exp2f(sc0[r] - mn);
        p1[r] = __builtin_amdgcn_exp2f(sc1[r] - mn);
        rs[r] = p0[r] + p1[r];
      }
#pragma unroll
      for (int d = 1; d < 16; d <<= 1)
#pragma unroll
        for (int r = 0; r < 4; ++r) rs[r] += __shfl_xor(rs[r], d, 64);
#pragma unroll
      for (int r = 0; r < 4; ++r) {
        lr[r] = lr[r] * alpha[r] + rs[r];
        o0[r] *= alpha[r]; o1[r] *= alpha[r]; o2[r] *= alpha[r]; o3[r] *= alpha[r];
      }
      // ---- P: C-layout -> A-layout via LDS ----
#pragma unroll
      for (int r = 0; r < 4; ++r) {
        Pt[(quad * 4 + r) * 40 + l15]      = (__bf16)p0[r];
        Pt[(quad * 4 + r) * 40 + 16 + l15] = (__bf16)p1[r];
      }
      __syncthreads();  // single wave: cheap; forces write->read ordering
      const bf16x8 pa = *(const bf16x8*)(Pt + l15 * 40 + quad * 8);
      // ---- O += P V : B-frags straight from vt[b][h][t] ----
      const u16* vb = vt + ((size_t)(b * H_ + l15)) * T_ + s0 + quad * 8;
      const bf16x8 bv0 = *(const bf16x8*)(vb);
      const bf16x8 bv1 = *(const bf16x8*)(vb + 16 * T_);
      const bf16x8 bv2 = *(const bf16x8*)(vb + 32 * T_);
      const bf16x8 bv3 = *(const bf16x8*)(vb + 48 * T_);
      o0 = __builtin_amdgcn_mfma_f32_16x16x32_bf16(pa, bv0, o0, 0, 0, 0);
      o1 = __builtin_amdgcn_mfma_f32_16x16x32_bf16(pa, bv1, o1, 0, 0, 0);
      o2 = __builtin_amdgcn_mfma_f32_16x16x32_bf16(pa, bv2, o2, 0, 0, 0);
      o3 = __builtin_amdgcn_mfma_f32_16x16x32_bf16(pa, bv3, o3, 0, 0, 0);
      __syncthreads();  // protect Pt before next iteration's writes
    }
    // ---- epilogue: divide by l, store fp32 ----
    float* ob = out + ((size_t)b * T_ + t0 + quad * 4) * H_ + l15;
#pragma unroll
    for (int r = 0; r < 4; ++r) {
      const float inv = 1.0f / lr[r];
      ob[(size_t)r * H_ + 0]  = o0[r] * inv;
      ob[(size_t)r * H_ + 16] = o1[r] * inv;
      ob[(size_t)r * H_ + 32] = o2[r] * inv;
      ob[(size_t)r * H_ + 48] = o3[r] * inv;
    }
  }
}

extern "C" void kernel_launch(void* const* d_in, const int* in_sizes, int n_in,
                              void* d_out, int out_size, void* d_ws, size_t ws_size,
                              hipStream_t stream) {
  const float* x  = (const float*)d_in[0];
  const float* Wk = (const float*)d_in[1];
  const float* Wq = (const float*)d_in[2];
  const float* Wv = (const float*)d_in[3];
  u16*   ws  = (u16*)d_ws;
  float* out = (float*)d_out;
  qkv_proj<<<dim3(3, (B_ * T_) / 16), dim3(64, 4), 0, stream>>>(x, Wk, Wq, Wv, ws);
  flash<<<dim3(64, B_), dim3(64), 0, stream>>>(ws, out);
}

// Round 2
// 207.188 us; speedup vs baseline: 2.8210x; 2.8210x over previous
//
#include <hip/hip_runtime.h>

// Head attention forward, MI355X gfx950.
// B=8, T=2048, C=1024, H=64. Scale = C^-0.5 = 1/32.
// R2 structure:
//   wpack:    Wk|Wq|Wv fp32 -> bf16 Wct[192][1024] (transposed, b128-friendly)
//   qkv_gemm: bf16 MFMA GEMM [16384x1024]@Wct^T -> bf16 k,q (row) + vt (transposed)
//   flash:    bf16-MFMA flash attn, 64-key s-steps, reg-prefetch K/V, wave-local
//             LDS fence (no __syncthreads -> no vmcnt(0) drain, prefetch survives)
//
// ws layout (u16/bf16):
//   [0      , BTH)     k   [b][t][h]
//   [BTH    , 2*BTH)   q   [b][t][h]
//   [2*BTH  , 3*BTH)   vt  [b][h][t]
//   [3*BTH  , +192K)   Wct [n][k]   n: 0..63=Wk col, 64..127=Wq, 128..191=Wv

#define B_ 8
#define T_ 2048
#define C_ 1024
#define H_ 64
#define BTH (B_ * T_ * H_)

typedef unsigned short u16;
typedef float f32x4 __attribute__((ext_vector_type(4)));
typedef __bf16 bf16x8 __attribute__((ext_vector_type(8)));

__device__ __forceinline__ u16 f2bf(float f) {
  union { float f; unsigned u; } c; c.f = f;
  unsigned u = c.u;
  return (u16)((u + 0x7FFFu + ((u >> 16) & 1u)) >> 16);  // RNE
}

__device__ __forceinline__ bf16x8 cvt8(const float4 a, const float4 b) {
  bf16x8 r;
  r[0] = (__bf16)a.x; r[1] = (__bf16)a.y; r[2] = (__bf16)a.z; r[3] = (__bf16)a.w;
  r[4] = (__bf16)b.x; r[5] = (__bf16)b.y; r[6] = (__bf16)b.z; r[7] = (__bf16)b.w;
  return r;
}

// ---------------------------------------------------------------------------
// wpack: Wct[g*64+h][k] = W_g[k][h], bf16. grid (3,16), block 256. ~0.4 MB out.
// ---------------------------------------------------------------------------
__global__ __launch_bounds__(256)
void wpack(const float* __restrict__ Wk, const float* __restrict__ Wq,
           const float* __restrict__ Wv, u16* __restrict__ Wct) {
  const int g  = blockIdx.x;
  const int k0 = blockIdx.y * 64;
  const float* __restrict__ W = (g == 0) ? Wk : (g == 1) ? Wq : Wv;
#pragma unroll
  for (int it = 0; it < 16; ++it) {
    const int idx = it * 256 + threadIdx.x;
    const int kk = k0 + (idx >> 6), h = idx & 63;
    Wct[(size_t)(g * 64 + h) * C_ + kk] = f2bf(W[(size_t)kk * H_ + h]);
  }
}

// ---------------------------------------------------------------------------
// qkv_gemm: grid (512), block 256 (4 waves). Wave: 16 rows x 96 cols.
//   rows r0 = bx*32 + (wave>>1)*16; cols c0 = (wave&1)*96.
// A-frag: x[r0+l15][k0+quad*8+j] fp32 -> bf16 in reg.
// B-frag: Wct[c0+16ni+l15][k0+quad*8+j] b128.
// Store: cols 0..63 -> k, 64..127 -> q (row-major), 128..191 -> vt (transposed).
// ---------------------------------------------------------------------------
__global__ __launch_bounds__(256)
void qkv_gemm(const float* __restrict__ x, const u16* __restrict__ Wct,
              u16* __restrict__ ws) {
  const int tid  = threadIdx.x;
  const int wave = tid >> 6, lane = tid & 63;
  const int l15 = lane & 15, quad = lane >> 4;
  const int r0 = blockIdx.x * 32 + (wave >> 1) * 16;
  const int c0 = (wave & 1) * 96;
  const float* xp = x + (size_t)(r0 + l15) * C_ + quad * 8;
  const u16*   wp = Wct + (size_t)(c0 + l15) * C_ + quad * 8;
  const f32x4 z = {0.f, 0.f, 0.f, 0.f};
  f32x4 acc[6];
#pragma unroll
  for (int ni = 0; ni < 6; ++ni) acc[ni] = z;
#pragma unroll 2
  for (int kk = 0; kk < C_; kk += 32) {
    const float4 xa = *(const float4*)xp;
    const float4 xb = *(const float4*)(xp + 4);
    const bf16x8 af = cvt8(xa, xb);
#pragma unroll
    for (int ni = 0; ni < 6; ++ni) {
      const bf16x8 bfr = *(const bf16x8*)(wp + (size_t)ni * 16 * C_);
      acc[ni] = __builtin_amdgcn_mfma_f32_16x16x32_bf16(af, bfr, acc[ni], 0, 0, 0);
    }
    xp += 32; wp += 32;
  }
  const int bb = r0 >> 11;                 // batch (rows of a block share b: 32|2048)
  const int tb = (r0 & 2047) + quad * 4;   // t of reg 0
#pragma unroll
  for (int ni = 0; ni < 6; ++ni) {
    const int col = c0 + ni * 16 + l15;
    const int g = col >> 6, h = col & 63;  // g wave-uniform (16-col tile within 64-group)
    if (g < 2) {
      u16* op = ws + (size_t)g * BTH + (size_t)(r0 + quad * 4) * H_ + h;
#pragma unroll
      for (int r = 0; r < 4; ++r) op[(size_t)r * H_] = f2bf(acc[ni][r]);
    } else {
      uint2 pk;
      pk.x = (unsigned)f2bf(acc[ni][0]) | ((unsigned)f2bf(acc[ni][1]) << 16);
      pk.y = (unsigned)f2bf(acc[ni][2]) | ((unsigned)f2bf(acc[ni][3]) << 16);
      *(uint2*)(ws + (size_t)2 * BTH + (size_t)(bb * H_ + h) * T_ + tb) = pk;
    }
  }
}

// ---------------------------------------------------------------------------
// flash: grid (128, 8), block 64 (1 wave). qt = 127-bx (heavy tiles dispatch
// first). 64-key s-steps, nst = (qt+4)>>2. K/V double-buffered in registers,
// prefetch issued before softmax. P relayout via per-wave LDS with
// s_waitcnt lgkmcnt(0) fence (DS ops in-order per wave; no barrier ->
// prefetch vmcnt stays in flight).
// ---------------------------------------------------------------------------
__device__ __forceinline__ void flash_step(
    int st, int nst, int t0, int l15, int quad,
    const u16* __restrict__ kb0, const u16* __restrict__ vb0,
    const bf16x8 qf0, const bf16x8 qf1,
    bf16x8 (&kc)[8], bf16x8 (&vc)[8],
    bf16x8 (&kn)[8], bf16x8 (&vn)[8],
    f32x4 (&o)[4], float (&mr)[4], float (&lr)[4], __bf16* Pt) {
  const int s0 = st * 64;
  const f32x4 z = {0.f, 0.f, 0.f, 0.f};
  f32x4 s[4];
#pragma unroll
  for (int ni = 0; ni < 4; ++ni) {
    s[ni] = __builtin_amdgcn_mfma_f32_16x16x32_bf16(qf0, kc[2 * ni], z, 0, 0, 0);
    s[ni] = __builtin_amdgcn_mfma_f32_16x16x32_bf16(qf1, kc[2 * ni + 1], s[ni], 0, 0, 0);
  }
  const bool last = (st == nst - 1);
  if (!last) {  // prefetch next K/V tiles; latency hides behind softmax below
    const int s1 = s0 + 64;
#pragma unroll
    for (int ni = 0; ni < 4; ++ni) {
      const u16* kp = kb0 + (size_t)(s1 + 16 * ni + l15) * H_ + quad * 8;
      kn[2 * ni]     = *(const bf16x8*)kp;
      kn[2 * ni + 1] = *(const bf16x8*)(kp + 32);
      const u16* vp = vb0 + (size_t)(16 * ni + l15) * T_ + s1 + quad * 8;
      vn[2 * ni]     = *(const bf16x8*)vp;
      vn[2 * ni + 1] = *(const bf16x8*)(vp + 32);
    }
  }
  const float SCL = 0.03125f * 1.44269504088896f;  // C^-0.5 * log2(e)
  float sc[4][4];
#pragma unroll
  for (int ni = 0; ni < 4; ++ni)
#pragma unroll
    for (int r = 0; r < 4; ++r) sc[ni][r] = s[ni][r] * SCL;
  if (last) {
#pragma unroll
    for (int ni = 0; ni < 4; ++ni)
#pragma unroll
      for (int r = 0; r < 4; ++r) {
        const int t = t0 + quad * 4 + r;
        if (s0 + 16 * ni + l15 > t) sc[ni][r] = -1e30f;
      }
  }
  float mx[4];
#pragma unroll
  for (int r = 0; r < 4; ++r)
    mx[r] = fmaxf(fmaxf(sc[0][r], sc[1][r]), fmaxf(sc[2][r], sc[3][r]));
#pragma unroll
  for (int d = 1; d < 16; d <<= 1)
#pragma unroll
    for (int r = 0; r < 4; ++r) mx[r] = fmaxf(mx[r], __shfl_xor(mx[r], d, 64));
  float p[4][4], alpha[4], rs[4];
#pragma unroll
  for (int r = 0; r < 4; ++r) {
    const float mn = fmaxf(mr[r], mx[r]);
    alpha[r] = __builtin_amdgcn_exp2f(mr[r] - mn);
    mr[r] = mn;
#pragma unroll
    for (int ni = 0; ni < 4; ++ni) p[ni][r] = __builtin_amdgcn_exp2f(sc[ni][r] - mn);
    rs[r] = (p[0][r] + p[1][r]) + (p[2][r] + p[3][r]);
  }
#pragma unroll
  for (int d = 1; d < 16; d <<= 1)
#pragma unroll
    for (int r = 0; r < 4; ++r) rs[r] += __shfl_xor(rs[r], d, 64);
#pragma unroll
  for (int r = 0; r < 4; ++r) {
    lr[r] = lr[r] * alpha[r] + rs[r];
    o[0][r] *= alpha[r]; o[1][r] *= alpha[r]; o[2][r] *= alpha[r]; o[3][r] *= alpha[r];
  }
  // P: C-layout -> A-layout via per-wave LDS (stride 72 hw = 144 B, 16B-aligned)
#pragma unroll
  for (int ni = 0; ni < 4; ++ni)
#pragma unroll
    for (int r = 0; r < 4; ++r)
      Pt[(quad * 4 + r) * 72 + ni * 16 + l15] = (__bf16)p[ni][r];
  asm volatile("s_waitcnt lgkmcnt(0)" ::: "memory");  // wave-local write->read fence
  const bf16x8 pa0 = *(const bf16x8*)(Pt + l15 * 72 + quad * 8);
  const bf16x8 pa1 = *(const bf16x8*)(Pt + l15 * 72 + 32 + quad * 8);
  asm volatile("" ::: "memory");  // keep reads emitted before next iter's writes
#pragma unroll
  for (int ni = 0; ni < 4; ++ni) {
    o[ni] = __builtin_amdgcn_mfma_f32_16x16x32_bf16(pa0, vc[2 * ni], o[ni], 0, 0, 0);
    o[ni] = __builtin_amdgcn_mfma_f32_16x16x32_bf16(pa1, vc[2 * ni + 1], o[ni], 0, 0, 0);
  }
}

__global__ __launch_bounds__(64)
void flash(const u16* __restrict__ ws, float* __restrict__ out) {
  const u16* __restrict__ kg = ws;
  const u16* __restrict__ qg = ws + BTH;
  const u16* __restrict__ vt = ws + (size_t)2 * BTH;
  const int b    = blockIdx.y;
  const int lane = threadIdx.x;
  const int l15  = lane & 15;
  const int quad = lane >> 4;
  __shared__ __bf16 Pt[16 * 72];
  const int qt = 127 - (int)blockIdx.x;  // heavy first
  const int t0 = qt * 16;
  const int nst = (qt + 4) >> 2;         // 64-key steps
  const u16* kb0 = kg + (size_t)b * T_ * H_;
  const u16* vb0 = vt + (size_t)b * H_ * T_;
  const u16* qrow = qg + ((size_t)(b * T_ + t0 + l15)) * H_ + quad * 8;
  const bf16x8 qf0 = *(const bf16x8*)qrow;
  const bf16x8 qf1 = *(const bf16x8*)(qrow + 32);
  const f32x4 z = {0.f, 0.f, 0.f, 0.f};
  f32x4 o[4];
  float mr[4], lr[4];
#pragma unroll
  for (int r = 0; r < 4; ++r) { mr[r] = -INFINITY; lr[r] = 0.f; }
#pragma unroll
  for (int ni = 0; ni < 4; ++ni) o[ni] = z;

  bf16x8 kA[8], vA[8], kB[8], vB[8];
#pragma unroll
  for (int ni = 0; ni < 4; ++ni) {  // preload s-tile 0
    const u16* kp = kb0 + (size_t)(16 * ni + l15) * H_ + quad * 8;
    kA[2 * ni]     = *(const bf16x8*)kp;
    kA[2 * ni + 1] = *(const bf16x8*)(kp + 32);
    const u16* vp = vb0 + (size_t)(16 * ni + l15) * T_ + quad * 8;
    vA[2 * ni]     = *(const bf16x8*)vp;
    vA[2 * ni + 1] = *(const bf16x8*)(vp + 32);
  }
  int st = 0;
  while (true) {  // ping-pong double buffer, all reg-array indices constant
    flash_step(st, nst, t0, l15, quad, kb0, vb0, qf0, qf1, kA, vA, kB, vB, o, mr, lr, Pt);
    if (++st == nst) break;
    flash_step(st, nst, t0, l15, quad, kb0, vb0, qf0, qf1, kB, vB, kA, vA, o, mr, lr, Pt);
    if (++st == nst) break;
  }
  float* ob = out + ((size_t)b * T_ + t0 + quad * 4) * H_ + l15;
#pragma unroll
  for (int r = 0; r < 4; ++r) {
    const float inv = 1.0f / lr[r];
#pragma unroll
    for (int ni = 0; ni < 4; ++ni)
      ob[(size_t)r * H_ + 16 * ni] = o[ni][r] * inv;
  }
}

extern "C" void kernel_launch(void* const* d_in, const int* in_sizes, int n_in,
                              void* d_out, int out_size, void* d_ws, size_t ws_size,
                              hipStream_t stream) {
  const float* x  = (const float*)d_in[0];
  const float* Wk = (const float*)d_in[1];
  const float* Wq = (const float*)d_in[2];
  const float* Wv = (const float*)d_in[3];
  u16*   ws  = (u16*)d_ws;
  u16*   Wct = ws + (size_t)3 * BTH;
  float* out = (float*)d_out;
  wpack<<<dim3(3, 16), 256, 0, stream>>>(Wk, Wq, Wv, Wct);
  qkv_gemm<<<dim3(512), 256, 0, stream>>>(x, Wct, ws);
  flash<<<dim3(128, B_), 64, 0, stream>>>(ws, out);
}

// Round 3
// 185.159 us; speedup vs baseline: 3.1567x; 1.1190x over previous
//
#include <hip/hip_runtime.h>

// Head attention forward, MI355X gfx950.
// B=8, T=2048, C=1024, H=64. Scale = C^-0.5 = 1/32.
// R3 structure:
//   wpack:    Wk|Wq|Wv fp32 -> bf16 Wct[192][1024] (transposed)
//   qkv_gemm: m97-style LDS-staged bf16 MFMA GEMM. 512 blocks x 8 waves,
//             32 rows x 192 cols, BK=64. x staged fp32 via global_load_lds
//             (16B) with XOR-swizzled chunk placement (conflict-free b128
//             reads despite the wave-uniform-base staging constraint).
//   flash:    split-K flash attention: 4 waves per q-tile, wave w handles
//             s-steps w, w+4, ...; partials combined via LDS.
//
// ws layout (u16/bf16):
//   [0      , BTH)     k   [b][t][h]
//   [BTH    , 2*BTH)   q   [b][t][h]
//   [2*BTH  , 3*BTH)   vt  [b][h][t]
//   [3*BTH  , +192K)   Wct [n][k]   n: 0..63=Wk col, 64..127=Wq, 128..191=Wv

#define B_ 8
#define T_ 2048
#define C_ 1024
#define H_ 64
#define BTH (B_ * T_ * H_)

typedef unsigned short u16;
typedef float f32x4 __attribute__((ext_vector_type(4)));
typedef __bf16 bf16x8 __attribute__((ext_vector_type(8)));
#define AS1 __attribute__((address_space(1)))
#define AS3 __attribute__((address_space(3)))

__device__ __forceinline__ u16 f2bf(float f) {
  union { float f; unsigned u; } c; c.f = f;
  unsigned u = c.u;
  return (u16)((u + 0x7FFFu + ((u >> 16) & 1u)) >> 16);  // RNE
}

__device__ __forceinline__ bf16x8 cvt8(const float4 a, const float4 b) {
  bf16x8 r;
  r[0] = (__bf16)a.x; r[1] = (__bf16)a.y; r[2] = (__bf16)a.z; r[3] = (__bf16)a.w;
  r[4] = (__bf16)b.x; r[5] = (__bf16)b.y; r[6] = (__bf16)b.z; r[7] = (__bf16)b.w;
  return r;
}

// ---------------------------------------------------------------------------
// wpack: Wct[g*64+h][k] = W_g[k][h], bf16. grid (3,16), block 256.
// ---------------------------------------------------------------------------
__global__ __launch_bounds__(256)
void wpack(const float* __restrict__ Wk, const float* __restrict__ Wq,
           const float* __restrict__ Wv, u16* __restrict__ Wct) {
  const int g  = blockIdx.x;
  const int k0 = blockIdx.y * 64;
  const float* __restrict__ W = (g == 0) ? Wk : (g == 1) ? Wq : Wv;
#pragma unroll
  for (int it = 0; it < 16; ++it) {
    const int idx = it * 256 + threadIdx.x;
    const int kk = k0 + (idx >> 6), h = idx & 63;
    Wct[(size_t)(g * 64 + h) * C_ + kk] = f2bf(W[(size_t)kk * H_ + h]);
  }
}

// ---------------------------------------------------------------------------
// qkv_gemm: grid (512), block 512 (8 waves). Block tile: 32 rows x 192 cols.
// Wave w: m-tile mt=w>>2 (16 rows), col-group cg=w&3 (48 cols = 3 B-frags).
// K-loop: 16 steps of BK=64. Per step: stage x[32][64] fp32 into LDS via
// global_load_lds (1x16B per thread), 2-barrier m97 loop.
// Swizzle: 16B chunk (row,kc) lives at slot row*16 + (kc&8 | ((kc&7)^(row&7))).
//   - staging: thread tid stages slot tid (source addr inverts the swizzle;
//     still 128B-coalesced since XOR permutes within a row's halves)
//   - A-read: ds_read_b128 per 16B chunk -> 8 lanes/bank-group (conflict-free)
// B-frags (Wct, 384KB L2-resident) read direct from global.
// ---------------------------------------------------------------------------
__global__ __launch_bounds__(512, 4)
void qkv_gemm(const float* __restrict__ x, const u16* __restrict__ Wct,
              u16* __restrict__ ws) {
  __shared__ float4 xs4[512];  // 32 rows x 16 chunks (swizzled), 8KB
  const int tid  = threadIdx.x;
  const int wave = tid >> 6, lane = tid & 63;
  const int l15 = lane & 15, quad = lane >> 4;
  const int mt = wave >> 2, cg = wave & 3;
  const int r0 = blockIdx.x * 32;
  // staging assignment: thread tid -> slot tid
  const int srow = tid >> 4, kcs = tid & 15;
  const int kcg  = (kcs & 8) | ((kcs & 7) ^ (srow & 7));  // global chunk idx
  const float* gp0 = x + (size_t)(r0 + srow) * C_ + kcg * 4;
  // A-read slots (wave-side): row = mt*16 + l15
  const int ar = mt * 16 + l15;
  const int sA00 = ar * 16 + 0 + ((quad * 2 + 0) ^ (l15 & 7));  // kh=0,h=0
  const int sA01 = ar * 16 + 0 + ((quad * 2 + 1) ^ (l15 & 7));  // kh=0,h=1
  const int sA10 = ar * 16 + 8 + ((quad * 2 + 0) ^ (l15 & 7));  // kh=1,h=0
  const int sA11 = ar * 16 + 8 + ((quad * 2 + 1) ^ (l15 & 7));  // kh=1,h=1
  const u16* wp = Wct + (size_t)(cg * 48 + l15) * C_ + quad * 8;
  const f32x4 z = {0.f, 0.f, 0.f, 0.f};
  f32x4 acc[3];
#pragma unroll
  for (int ni = 0; ni < 3; ++ni) acc[ni] = z;

  for (int ks = 0; ks < 16; ++ks) {
    const int k0 = ks * 64;
    __syncthreads();  // previous step's reads complete before overwrite
    __builtin_amdgcn_global_load_lds((const AS1 unsigned*)(gp0 + k0),
                                     (AS3 unsigned*)(&xs4[tid]), 16, 0, 0);
    __syncthreads();  // implies vmcnt(0): staged data visible
    const float4 a00 = xs4[sA00], a01 = xs4[sA01];
    const float4 a10 = xs4[sA10], a11 = xs4[sA11];
    const bf16x8 af0 = cvt8(a00, a01);
    const bf16x8 af1 = cvt8(a10, a11);
#pragma unroll
    for (int ni = 0; ni < 3; ++ni) {
      const bf16x8 b0 = *(const bf16x8*)(wp + (size_t)ni * 16 * C_ + k0);
      acc[ni] = __builtin_amdgcn_mfma_f32_16x16x32_bf16(af0, b0, acc[ni], 0, 0, 0);
      const bf16x8 b1 = *(const bf16x8*)(wp + (size_t)ni * 16 * C_ + k0 + 32);
      acc[ni] = __builtin_amdgcn_mfma_f32_16x16x32_bf16(af1, b1, acc[ni], 0, 0, 0);
    }
  }
  // epilogue: cols cg*48+ni*16+l15; g = col>>6 wave-uniform per ni
  const int rowg = r0 + mt * 16;
  const int bb = rowg >> 11;
  const int tb = (rowg & 2047) + quad * 4;
#pragma unroll
  for (int ni = 0; ni < 3; ++ni) {
    const int col = cg * 48 + ni * 16 + l15;
    const int g = col >> 6, h = col & 63;
    if (g < 2) {
      u16* op = ws + (size_t)g * BTH + (size_t)(rowg + quad * 4) * H_ + h;
#pragma unroll
      for (int r = 0; r < 4; ++r) op[(size_t)r * H_] = f2bf(acc[ni][r]);
    } else {
      uint2 pk;
      pk.x = (unsigned)f2bf(acc[ni][0]) | ((unsigned)f2bf(acc[ni][1]) << 16);
      pk.y = (unsigned)f2bf(acc[ni][2]) | ((unsigned)f2bf(acc[ni][3]) << 16);
      *(uint2*)(ws + (size_t)2 * BTH + (size_t)(bb * H_ + h) * T_ + tb) = pk;
    }
  }
}

// ---------------------------------------------------------------------------
// flash: grid (128, 8), block 256 (4 waves) per q-tile. qt = 127-bx (heavy
// first). Wave w handles s-steps w, w+4, ... (64 keys each, single-buffered
// K/V loads from L2). Partial (o, m, l) per wave combined via LDS.
// ---------------------------------------------------------------------------
__global__ __launch_bounds__(256)
void flash(const u16* __restrict__ ws, float* __restrict__ out) {
  const u16* __restrict__ kg = ws;
  const u16* __restrict__ qg = ws + BTH;
  const u16* __restrict__ vt = ws + (size_t)2 * BTH;
  __shared__ __bf16 Pt[4][16 * 72];
  __shared__ float  Ocmb[4][16][64];
  __shared__ float2 ml[4][16];
  const int b    = blockIdx.y;
  const int qt   = 127 - (int)blockIdx.x;
  const int t0   = qt * 16;
  const int nst  = (qt + 4) >> 2;  // 64-key steps
  const int tid  = threadIdx.x;
  const int w    = tid >> 6;
  const int lane = tid & 63;
  const int l15  = lane & 15, quad = lane >> 4;
  const u16* kb0 = kg + (size_t)b * T_ * H_;
  const u16* vb0 = vt + (size_t)b * H_ * T_;
  const u16* qrow = qg + ((size_t)(b * T_ + t0 + l15)) * H_ + quad * 8;
  const bf16x8 qf0 = *(const bf16x8*)qrow;
  const bf16x8 qf1 = *(const bf16x8*)(qrow + 32);
  __bf16* pt = &Pt[w][0];
  const float SCL = 0.03125f * 1.44269504088896f;  // C^-0.5 * log2(e)
  const f32x4 z = {0.f, 0.f, 0.f, 0.f};
  f32x4 o[4];
  float mr[4], lr[4];
#pragma unroll
  for (int r = 0; r < 4; ++r) { mr[r] = -INFINITY; lr[r] = 0.f; }
#pragma unroll
  for (int ni = 0; ni < 4; ++ni) o[ni] = z;

  for (int st = w; st < nst; st += 4) {
    const int s0 = st * 64;
    // K then V loads (V consumed after softmax -> latency overlaps VALU)
    bf16x8 kc[8], vc[8];
#pragma unroll
    for (int ni = 0; ni < 4; ++ni) {
      const u16* kp = kb0 + (size_t)(s0 + 16 * ni + l15) * H_ + quad * 8;
      kc[2 * ni]     = *(const bf16x8*)kp;
      kc[2 * ni + 1] = *(const bf16x8*)(kp + 32);
      const u16* vp = vb0 + (size_t)(16 * ni + l15) * T_ + s0 + quad * 8;
      vc[2 * ni]     = *(const bf16x8*)vp;
      vc[2 * ni + 1] = *(const bf16x8*)(vp + 32);
    }
    f32x4 s[4];
#pragma unroll
    for (int ni = 0; ni < 4; ++ni) {
      s[ni] = __builtin_amdgcn_mfma_f32_16x16x32_bf16(qf0, kc[2 * ni], z, 0, 0, 0);
      s[ni] = __builtin_amdgcn_mfma_f32_16x16x32_bf16(qf1, kc[2 * ni + 1], s[ni], 0, 0, 0);
    }
    float sc[4][4];
#pragma unroll
    for (int ni = 0; ni < 4; ++ni)
#pragma unroll
      for (int r = 0; r < 4; ++r) sc[ni][r] = s[ni][r] * SCL;
    if (st == nst - 1) {  // causal mask only on the globally-last tile
#pragma unroll
      for (int ni = 0; ni < 4; ++ni)
#pragma unroll
        for (int r = 0; r < 4; ++r) {
          const int t = t0 + quad * 4 + r;
          if (s0 + 16 * ni + l15 > t) sc[ni][r] = -1e30f;
        }
    }
    float mx[4];
#pragma unroll
    for (int r = 0; r < 4; ++r)
      mx[r] = fmaxf(fmaxf(sc[0][r], sc[1][r]), fmaxf(sc[2][r], sc[3][r]));
#pragma unroll
    for (int d = 1; d < 16; d <<= 1)
#pragma unroll
      for (int r = 0; r < 4; ++r) mx[r] = fmaxf(mx[r], __shfl_xor(mx[r], d, 64));
    float p[4][4], alpha[4], rs[4];
#pragma unroll
    for (int r = 0; r < 4; ++r) {
      const float mn = fmaxf(mr[r], mx[r]);
      alpha[r] = __builtin_amdgcn_exp2f(mr[r] - mn);
      mr[r] = mn;
#pragma unroll
      for (int ni = 0; ni < 4; ++ni) p[ni][r] = __builtin_amdgcn_exp2f(sc[ni][r] - mn);
      rs[r] = (p[0][r] + p[1][r]) + (p[2][r] + p[3][r]);
    }
#pragma unroll
    for (int d = 1; d < 16; d <<= 1)
#pragma unroll
      for (int r = 0; r < 4; ++r) rs[r] += __shfl_xor(rs[r], d, 64);
#pragma unroll
    for (int r = 0; r < 4; ++r) {
      lr[r] = lr[r] * alpha[r] + rs[r];
      o[0][r] *= alpha[r]; o[1][r] *= alpha[r]; o[2][r] *= alpha[r]; o[3][r] *= alpha[r];
    }
    // P: C-layout -> A-layout via per-wave LDS region (wave-local fence only)
#pragma unroll
    for (int ni = 0; ni < 4; ++ni)
#pragma unroll
      for (int r = 0; r < 4; ++r)
        pt[(quad * 4 + r) * 72 + ni * 16 + l15] = (__bf16)p[ni][r];
    asm volatile("s_waitcnt lgkmcnt(0)" ::: "memory");
    const bf16x8 pa0 = *(const bf16x8*)(pt + l15 * 72 + quad * 8);
    const bf16x8 pa1 = *(const bf16x8*)(pt + l15 * 72 + 32 + quad * 8);
    asm volatile("" ::: "memory");
#pragma unroll
    for (int ni = 0; ni < 4; ++ni) {
      o[ni] = __builtin_amdgcn_mfma_f32_16x16x32_bf16(pa0, vc[2 * ni], o[ni], 0, 0, 0);
      o[ni] = __builtin_amdgcn_mfma_f32_16x16x32_bf16(pa1, vc[2 * ni + 1], o[ni], 0, 0, 0);
    }
  }
  // publish partials
#pragma unroll
  for (int ni = 0; ni < 4; ++ni)
#pragma unroll
    for (int r = 0; r < 4; ++r)
      Ocmb[w][quad * 4 + r][ni * 16 + l15] = o[ni][r];
  if (l15 == 0) {
#pragma unroll
    for (int r = 0; r < 4; ++r) ml[w][quad * 4 + r] = make_float2(mr[r], lr[r]);
  }
  __syncthreads();
  // combine: thread handles col c for 4 rows
  const int c = tid & 63, rr = tid >> 6;
#pragma unroll
  for (int rb = 0; rb < 16; rb += 4) {
    const int row = rb + rr;
    const float2 m0 = ml[0][row], m1 = ml[1][row], m2 = ml[2][row], m3 = ml[3][row];
    const float m = fmaxf(fmaxf(m0.x, m1.x), fmaxf(m2.x, m3.x));
    const float s0w = __builtin_amdgcn_exp2f(m0.x - m);
    const float s1w = __builtin_amdgcn_exp2f(m1.x - m);
    const float s2w = __builtin_amdgcn_exp2f(m2.x - m);
    const float s3w = __builtin_amdgcn_exp2f(m3.x - m);
    const float l = s0w * m0.y + s1w * m1.y + s2w * m2.y + s3w * m3.y;
    const float ov = s0w * Ocmb[0][row][c] + s1w * Ocmb[1][row][c] +
                     s2w * Ocmb[2][row][c] + s3w * Ocmb[3][row][c];
    out[((size_t)b * T_ + t0 + row) * H_ + c] = ov / l;
  }
}

extern "C" void kernel_launch(void* const* d_in, const int* in_sizes, int n_in,
                              void* d_out, int out_size, void* d_ws, size_t ws_size,
                              hipStream_t stream) {
  const float* x  = (const float*)d_in[0];
  const float* Wk = (const float*)d_in[1];
  const float* Wq = (const float*)d_in[2];
  const float* Wv = (const float*)d_in[3];
  u16*   ws  = (u16*)d_ws;
  u16*   Wct = ws + (size_t)3 * BTH;
  float* out = (float*)d_out;
  wpack<<<dim3(3, 16), 256, 0, stream>>>(Wk, Wq, Wv, Wct);
  qkv_gemm<<<dim3(512), 512, 0, stream>>>(x, Wct, ws);
  flash<<<dim3(128, B_), 256, 0, stream>>>(ws, out);
}